// Round 9
// baseline (272.597 us; speedup 1.0000x reference)
//
#include <hip/hip_runtime.h>
#include <math.h>

typedef unsigned int u32;
typedef unsigned long long u64;
typedef unsigned char u8;

#define K_TOT 8382
#define NCH 131      // 131 chunks of 64 rows
#define CAP 1024     // per-source-chunk off-diag entry capacity
#define ECR 6        // register-prefetched entry slots per lane (384 entries/chunk)
#define DC 16        // per-chunk intra-chunk (diag) suppressor list capacity
#define GCAP 32768   // per-level threshold-bin candidate capacity
#define IMGSZ 800.0f

__device__ __constant__ int LOFF[5] = {0, 120000, 150000, 157500, 159375};
__device__ __constant__ int LCNT[5] = {120000, 30000, 7500, 1875, 507};
__device__ __constant__ int KSEL[5] = {2000, 2000, 2000, 1875, 507};
__device__ __constant__ int SELB[5] = {0, 2000, 4000, 6000, 7875};
__device__ __constant__ int HBS[4] = {0, 118, 148, 156};    // k_hist block starts (levels 0..2)
__device__ __constant__ int GBS[6] = {0, 118, 148, 156, 158, 159};  // k_gather block starts

static __device__ __forceinline__ u32 fkey(float x) {
    u32 u = __float_as_uint(x);
    u32 m = (u32)(((int)u) >> 31) | 0x80000000u;
    return u ^ m;
}

static __device__ __forceinline__ int lvl_of(int s) {
    return (s < 2000) ? 0 : (s < 4000) ? 1 : (s < 6000) ? 2 : (s < 7875) ? 3 : 4;
}

// scalar-path 64-bit readlane (uniform lane index -> v_readlane)
static __device__ __forceinline__ u64 rdlane64(u64 v, int j) {
    u32 lo = (u32)__builtin_amdgcn_readlane((int)(u32)v, j);
    u32 hi = (u32)__builtin_amdgcn_readlane((int)(u32)(v >> 32), j);
    return ((u64)hi << 32) | (u64)lo;
}

// Parallel reverse-inclusive scan over hist[0..m-1] (from top bin down);
// finds bin with suffix-cum >= need. Out: sv[0]=bin, sv[1]=remaining ties to take.
static __device__ __forceinline__ void thresh_scan(const u32* hist, u32* scanbuf, int m,
                                                   u32 need, u32* sv, int t) {
    for (int i = t; i < m; i += 1024) scanbuf[i] = hist[m - 1 - i];
    __syncthreads();
    for (int ofs = 1; ofs < m; ofs <<= 1) {
        int i0 = t, i1 = t + 1024;
        u32 a0 = 0, a1 = 0;
        if (i0 < m && i0 >= ofs) a0 = scanbuf[i0 - ofs];
        if (i1 < m && i1 >= ofs) a1 = scanbuf[i1 - ofs];
        __syncthreads();
        if (i0 < m && i0 >= ofs) scanbuf[i0] += a0;
        if (i1 < m && i1 >= ofs) scanbuf[i1] += a1;
        __syncthreads();
    }
    for (int i = t; i < m; i += 1024) {
        u32 inc = scanbuf[i];
        u32 exc = i ? scanbuf[i - 1] : 0;
        if (inc >= need && exc < need) { sv[0] = (u32)(m - 1 - i); sv[1] = need - exc; }
    }
    __syncthreads();
}

// ---------------- K1a: parallel coarse histogram (top 11 key bits), levels 0..2 ----------------
__global__ __launch_bounds__(1024) void k_hist(const float* __restrict__ scores,
                                               u32* __restrict__ hist3) {
    __shared__ u32 lh[2048];
    int t = threadIdx.x;
    lh[t] = 0; lh[t + 1024] = 0;
    __syncthreads();
    int b = blockIdx.x;
    int l = (b < HBS[1]) ? 0 : (b < HBS[2]) ? 1 : 2;
    int i = (b - HBS[l]) * 1024 + t;
    if (i < LCNT[l]) atomicAdd(&lh[fkey(scores[LOFF[l] + i]) >> 21], 1u);
    __syncthreads();
    u32* h = hist3 + l * 2048;
    if (lh[t]) atomicAdd(&h[t], lh[t]);
    if (lh[t + 1024]) atomicAdd(&h[t + 1024], lh[t + 1024]);
}

// ---------------- K1b: coarse threshold per level ----------------
__global__ __launch_bounds__(1024) void k_thresh(const u32* __restrict__ hist3,
                                                 u32* __restrict__ tinfo) {
    __shared__ u32 scanbuf[2048];
    __shared__ u32 sv[2];
    int l = blockIdx.x;
    int t = threadIdx.x;
    thresh_scan(hist3 + l * 2048, scanbuf, 2048, (u32)KSEL[l], sv, t);
    if (t == 0) { tinfo[l * 2] = sv[0]; tinfo[l * 2 + 1] = sv[1]; }
}

// ---------------- K1c: classify; strict-greater -> sel, threshold-bin -> candidate buf ----------------
__global__ __launch_bounds__(1024) void k_gather(const float* __restrict__ scores,
                                                 const u32* __restrict__ tinfo,
                                                 u32* __restrict__ sel, u32* __restrict__ cgt,
                                                 u32* __restrict__ gcnt, u32* __restrict__ gidx,
                                                 u32* __restrict__ gkey) {
    int b = blockIdx.x;
    int l = (b < GBS[1]) ? 0 : (b < GBS[2]) ? 1 : (b < GBS[3]) ? 2 : (b < GBS[4]) ? 3 : 4;
    int i = (b - GBS[l]) * 1024 + threadIdx.x;
    if (i >= LCNT[l]) return;
    int off = LOFF[l], sb = SELB[l];
    if (l >= 3) { sel[sb + i] = (u32)(off + i); return; }  // take-all levels
    u32 ky = fkey(scores[off + i]);
    u32 b1 = tinfo[l * 2];
    u32 top = ky >> 21;
    if (top > b1) {
        u32 p = atomicAdd(&cgt[l], 1u);
        sel[sb + p] = (u32)(off + i);          // set membership only; order fixed by P later
    } else if (top == b1) {
        u32 e = atomicAdd(&gcnt[l], 1u);
        if (e < GCAP) { gidx[l * GCAP + e] = (u32)i; gkey[l * GCAP + e] = ky; }
    }
}

// ---------------- K1d: exact refine within threshold bin (mid 11 + low 10 bits) ----------------
__global__ __launch_bounds__(1024) void k_final(const u32* __restrict__ gidx,
                                                const u32* __restrict__ gkey,
                                                const u32* __restrict__ gcnt,
                                                const u32* __restrict__ tinfo,
                                                u32* __restrict__ sel) {
    __shared__ u32 hist[2048];
    __shared__ u32 scanbuf[2048];
    __shared__ u32 eqbuf[1024];
    __shared__ u32 sv[2];
    __shared__ u32 c2, ceq;
    int l = blockIdx.x;
    int t = threadIdx.x;
    int k = KSEL[l], sb = SELB[l], off = LOFF[l];
    u32 m = gcnt[l]; if (m > GCAP) m = GCAP;
    u32 b1 = tinfo[l * 2];
    u32 need = tinfo[l * 2 + 1];
    const u32* kb = gkey + l * GCAP;
    const u32* ib = gidx + l * GCAP;
    // mid 11 bits
    hist[t] = 0; hist[t + 1024] = 0; __syncthreads();
    for (u32 e = t; e < m; e += 1024) atomicAdd(&hist[(kb[e] >> 10) & 2047u], 1u);
    __syncthreads();
    thresh_scan(hist, scanbuf, 2048, need, sv, t);
    u32 b2 = sv[0], need2 = sv[1];
    __syncthreads();
    // low 10 bits
    hist[t] = 0; __syncthreads();
    for (u32 e = t; e < m; e += 1024) {
        u32 ky = kb[e];
        if (((ky >> 10) & 2047u) == b2) atomicAdd(&hist[ky & 1023u], 1u);
    }
    __syncthreads();
    thresh_scan(hist, scanbuf, 1024, need2, sv, t);
    u32 T = (b1 << 21) | (b2 << 10) | sv[0];
    u32 take = sv[1];
    if (t == 0) { c2 = 0; ceq = 0; }
    __syncthreads();
    u32 nGTbin = need - take;
    u32 base2 = (u32)sb + (u32)k - need;   // after strict-greater-bin entries
    for (u32 e = t; e < m; e += 1024) {
        u32 ky = kb[e];
        if (ky > T) { u32 p = atomicAdd(&c2, 1u); sel[base2 + p] = (u32)off + ib[e]; }
        else if (ky == T) { u32 q = atomicAdd(&ceq, 1u); if (q < 1024) eqbuf[q] = ib[e]; }
    }
    __syncthreads();
    if (t == 0) {
        int n = (ceq > 1024u) ? 1024 : (int)ceq;
        for (int a = 1; a < n; ++a) {  // ascending insertion sort; tie count tiny
            u32 v = eqbuf[a]; int bq = a - 1;
            while (bq >= 0 && eqbuf[bq] > v) { eqbuf[bq + 1] = eqbuf[bq]; --bq; }
            eqbuf[bq + 1] = v;
        }
        for (u32 q = 0; q < take; ++q) sel[base2 + nGTbin + q] = (u32)off + eqbuf[q];
    }
}

// ---------------- K2: decode selected boxes (exact reference op order) ----------------
__global__ void k_decode(const float* __restrict__ scores, const float4* __restrict__ deltas,
                         const float4* __restrict__ anchors, const u32* __restrict__ sel,
                         float4* __restrict__ candB, float* __restrict__ candS,
                         u32* __restrict__ candV, u32* __restrict__ candA) {
    int s = blockIdx.x * 256 + threadIdx.x;
    if (s >= K_TOT) return;
    u32 a = sel[s];
    float4 an = anchors[a];
    float4 dl = deltas[a];
    float sc = scores[a];
    float w = __fsub_rn(an.z, an.x), h = __fsub_rn(an.w, an.y);
    float cx = __fadd_rn(an.x, __fmul_rn(0.5f, w));
    float cy = __fadd_rn(an.y, __fmul_rn(0.5f, h));
    const float CLIPV = (float)4.1351665567423563;  // log(1000/16) as f32
    float dw = fminf(dl.z, CLIPV);
    float dh = fminf(dl.w, CLIPV);
    float px = __fadd_rn(cx, __fmul_rn(dl.x, w));
    float py = __fadd_rn(cy, __fmul_rn(dl.y, h));
    float pw = __fmul_rn((float)exp((double)dw), w);
    float ph = __fmul_rn((float)exp((double)dh), h);
    float x1 = __fsub_rn(px, __fmul_rn(0.5f, pw));
    float y1 = __fsub_rn(py, __fmul_rn(0.5f, ph));
    float x2 = __fadd_rn(px, __fmul_rn(0.5f, pw));
    float y2 = __fadd_rn(py, __fmul_rn(0.5f, ph));
    x1 = fminf(fmaxf(x1, 0.0f), IMGSZ);
    y1 = fminf(fmaxf(y1, 0.0f), IMGSZ);
    x2 = fminf(fmaxf(x2, 0.0f), IMGSZ);
    y2 = fminf(fmaxf(y2, 0.0f), IMGSZ);
    bool valid = (__fsub_rn(x2, x1) >= 0.001f) && (__fsub_rn(y2, y1) >= 0.001f);
    candB[s] = make_float4(x1, y1, x2, y2);
    candS[s] = sc;
    candV[s] = valid ? 1u : 0u;
    candA[s] = a;
}

// ---------------- K3a: within-level rank (tiled pairwise count) ----------------
__global__ __launch_bounds__(256) void k_rank_lvl(const float* __restrict__ candS,
                                                  const u32* __restrict__ candA,
                                                  u32* __restrict__ Praw) {
    __shared__ u64 tile[256];
    int l = blockIdx.z;
    int cnt = KSEL[l], base = SELB[l];
    int tx = blockIdx.x * 256;
    int ty = blockIdx.y * 256;
    if (tx >= cnt || ty >= cnt) return;
    int t = threadIdx.x;
    u64 Aj = ~0ull;  // sentinel: never < any real key
    if (tx + t < cnt) {
        int j = base + tx + t;
        Aj = ((u64)(~fkey(candS[j])) << 32) | (u64)candA[j];
    }
    tile[t] = Aj;
    __syncthreads();
    int si = ty + t;
    if (si >= cnt) return;
    int s = base + si;
    u64 A = ((u64)(~fkey(candS[s])) << 32) | (u64)candA[s];
    int r = 0;
#pragma unroll 8
    for (int q = 0; q < 256; ++q) r += (tile[q] < A);
    if (r) atomicAdd(&Praw[s], (u32)r);
}

// ---------------- K3b: global rank by (masked score desc, position asc) ----------------
__global__ __launch_bounds__(256) void k_rank_glob(const float* __restrict__ candS,
                                                   const u32* __restrict__ candV,
                                                   const u32* __restrict__ Praw,
                                                   u32* __restrict__ rank) {
    __shared__ u64 colB[256];
    int t = threadIdx.x;
    int cj = blockIdx.x * 256 + t;
    u64 B = ~0ull;
    if (cj < K_TOT) {
        u32 smk = candV[cj] ? fkey(candS[cj]) : 0x007FFFFFu;  // fkey(-inf)
        u32 Pj = (u32)SELB[lvl_of(cj)] + Praw[cj];
        B = ((u64)(~smk) << 32) | (u64)Pj;
    }
    colB[t] = B;
    __syncthreads();
    int s = blockIdx.y * 256 + t;
    if (s >= K_TOT) return;
    u32 smk = candV[s] ? fkey(candS[s]) : 0x007FFFFFu;
    u32 Ps = (u32)SELB[lvl_of(s)] + Praw[s];
    u64 myB = ((u64)(~smk) << 32) | (u64)Ps;
    int cnt = 0;
#pragma unroll 8
    for (int j = 0; j < 256; ++j) cnt += (colB[j] < myB);
    if (cnt) atomicAdd(&rank[s], (u32)cnt);
}

// ---------------- K4: scatter into sorted order ----------------
// Reference's fmask slice is all zeros -> NMS on raw clipped boxes (no level offsets).
__global__ void k_scatter(const float4* __restrict__ candB, const float* __restrict__ candS,
                          const u32* __restrict__ candV, const u32* __restrict__ rank,
                          float4* __restrict__ sB, float* __restrict__ sArea,
                          float* __restrict__ sS, u32* __restrict__ sV) {
    int s = blockIdx.x * 256 + threadIdx.x;
    if (s >= K_TOT) return;
    u32 r = rank[s];
    float4 b = candB[s];
    float area = __fmul_rn(__fsub_rn(b.z, b.x), __fsub_rn(b.w, b.y));
    sB[r] = b; sArea[r] = area; sS[r] = candS[s]; sV[r] = candV[s];
}

// ---------------- K4b: valid bits -> words ----------------
__global__ void k_vwords(const u32* __restrict__ sV, u64* __restrict__ vwords) {
    int i = blockIdx.x * 64 + threadIdx.x;
    bool pred = (i < K_TOT) && sV[i];
    u64 bw = __ballot(pred);
    if (threadIdx.x == 0) vwords[blockIdx.x] = bw;
}

// ---------------- K5: suppression bits -> packed entry lists ----------------
// off-diag: bucketed by SOURCE chunk, 16B entries {row|target<<6, bits}.
// diag (intra-chunk): 16B list entries {lane, bits} + dmask; full diag[] kept as fallback.
__global__ __launch_bounds__(256) void k_mask(const float4* __restrict__ sB,
                                              const float* __restrict__ sArea,
                                              u64* __restrict__ diag, u32* __restrict__ ecnt,
                                              ulonglong2* __restrict__ epack,
                                              u32* __restrict__ dcnt, u64* __restrict__ dmask,
                                              ulonglong2* __restrict__ dpack) {
    __shared__ float4 cb[64];
    __shared__ float ca[64];
    int wd = blockIdx.x;   // target word (column chunk)
    int t = threadIdx.x;
    if (t < 64) {
        int j = wd * 64 + t;
        if (j < K_TOT) { cb[t] = sB[j]; ca[t] = sArea[j]; }
        else { cb[t] = make_float4(0.f, 0.f, 0.f, 0.f); ca[t] = 0.f; }
    }
    __syncthreads();
    int i = blockIdx.y * 256 + t;
    if (i >= K_TOT) return;
    int dwr = i >> 6;
    if (wd < dwr) return;  // strictly upper-triangular
    float4 bi = sB[i];
    float ai = sArea[i];
    u64 bits = 0;
    int jbase = wd * 64;
    for (int j2 = 0; j2 < 64; ++j2) {
        int j = jbase + j2;
        if (j > i && j < K_TOT) {
            float4 bj = cb[j2];
            float ltx = fmaxf(bi.x, bj.x), lty = fmaxf(bi.y, bj.y);
            float rbx = fminf(bi.z, bj.z), rby = fminf(bi.w, bj.w);
            float wx = fmaxf(__fsub_rn(rbx, ltx), 0.0f);
            float wy = fmaxf(__fsub_rn(rby, lty), 0.0f);
            float inter = __fmul_rn(wx, wy);
            if (inter > 0.0f) {
                float uni = __fsub_rn(__fadd_rn(ai, ca[j2]), inter);
                float iou = inter / uni;  // IEEE f32 div, matches reference
                if (iou > 0.7f) bits |= (1ull << j2);
            }
        }
    }
    if (wd == dwr) {
        diag[i] = bits;  // always stored (overflow fallback)
        if (bits != 0ull) {
            u32 p = atomicAdd(&dcnt[dwr], 1u);
            if (p < DC) dpack[dwr * DC + p] = make_ulonglong2((u64)(i & 63), bits);
            atomicOr(&dmask[dwr], 1ull << (i & 63));
        }
    } else if (bits != 0ull) {
        u32 p = atomicAdd(&ecnt[dwr], 1u);
        if (p < CAP) epack[dwr * CAP + p] = make_ulonglong2((u64)((i & 63) | (wd << 6)), bits);
    }
}

// ---------------- K6: sequential NMS scan — single wave, register-prefetch, tiny LDS ----------------
__global__ __launch_bounds__(64) void k_scan(const u64* __restrict__ diag,
                                             const u64* __restrict__ vwords,
                                             const u32* __restrict__ ecnt,
                                             const ulonglong2* __restrict__ epack,
                                             const u32* __restrict__ dcnt,
                                             const u64* __restrict__ dmask,
                                             const ulonglong2* __restrict__ dpack,
                                             u64* __restrict__ keepw) {
    __shared__ u64 sVw[NCH];
    __shared__ u32 sCnt[NCH];
    __shared__ u32 sDn[NCH];
    __shared__ u64 sDm[NCH];
    volatile __shared__ u64 sR[NCH];   // accumulated incoming suppression per chunk
    __shared__ u64 sKeep[NCH];
    int lane = threadIdx.x;
    // batched small preload: 3 straight-line rounds; loads issued together, then writes
    {
        int i0 = lane, i1 = lane + 64, i2 = lane + 128;
        bool p2 = (i2 < NCH);
        u64 v0 = vwords[i0], v1 = vwords[i1], v2 = p2 ? vwords[i2] : 0;
        u32 c0 = ecnt[i0], c1 = ecnt[i1], c2 = p2 ? ecnt[i2] : 0;
        u32 d0 = dcnt[i0], d1 = dcnt[i1], d2 = p2 ? dcnt[i2] : 0;
        u64 m0 = dmask[i0], m1 = dmask[i1], m2 = p2 ? dmask[i2] : 0;
        sVw[i0] = v0; sCnt[i0] = (c0 > CAP) ? CAP : c0; sDn[i0] = d0; sDm[i0] = m0; sR[i0] = 0;
        sVw[i1] = v1; sCnt[i1] = (c1 > CAP) ? CAP : c1; sDn[i1] = d1; sDm[i1] = m1; sR[i1] = 0;
        if (p2) { sVw[i2] = v2; sCnt[i2] = (c2 > CAP) ? CAP : c2; sDn[i2] = d2; sDm[i2] = m2; sR[i2] = 0; }
    }
    __syncthreads();
    // register entry pipeline, distance 2; slots gated by per-chunk count (no junk fetch)
    ulonglong2 E0[ECR], E1[ECR], DP0, DP1;
    u32 cnt0 = sCnt[0], cnt1 = sCnt[1];
#pragma unroll
    for (int s = 0; s < ECR; ++s) {
        E0[s] = ((u32)(s * 64) < cnt0) ? epack[0 * CAP + s * 64 + lane] : make_ulonglong2(0, 0);
        E1[s] = ((u32)(s * 64) < cnt1) ? epack[1 * CAP + s * 64 + lane] : make_ulonglong2(0, 0);
    }
    DP0 = (lane < DC) ? dpack[0 * DC + lane] : make_ulonglong2(0, 0);
    DP1 = (lane < DC) ? dpack[1 * DC + lane] : make_ulonglong2(0, 0);
    for (int c = 0; c < NCH; ++c) {
        // issue chunk c+2 prefetch (state-independent)
        ulonglong2 E2[ECR], DP2 = make_ulonglong2(0, 0);
        u32 cnt2 = 0;
        if (c + 2 < NCH) {
            cnt2 = sCnt[c + 2];
#pragma unroll
            for (int s = 0; s < ECR; ++s)
                E2[s] = ((u32)(s * 64) < cnt2) ? epack[(c + 2) * CAP + s * 64 + lane]
                                               : make_ulonglong2(0, 0);
            if (lane < DC) DP2 = dpack[(c + 2) * DC + lane];
        } else {
#pragma unroll
            for (int s = 0; s < ECR; ++s) E2[s] = make_ulonglong2(0, 0);
        }
        // the ONLY state-dependent read: incoming suppression accumulated so far
        u64 alive = sVw[c] & ~sR[c];
        // intra-chunk sequential resolve via register list (fallback: global diag)
        u32 dn = sDn[c];  // uniform
        if (dn) {
            if (dn <= (u32)DC) {
                u64 dm = sDm[c];                     // uniform: rows with nonzero diag word
                u32 ml = ((u32)lane < dn) ? (u32)DP0.x : 0xFFu;
                u64 mb = DP0.y;
                while (dm) {
                    int j = __builtin_ctzll(dm);
                    dm &= dm - 1;
                    if ((alive >> j) & 1ull) {       // uniform branch
                        u64 selm = __ballot(ml == (u32)j);
                        int src = __builtin_ctzll(selm);
                        alive &= ~rdlane64(mb, src);
                    }
                }
            } else {                                  // overflow: read full diag words (rare)
                int r = c * 64 + lane;
                u64 D = (r < K_TOT) ? diag[r] : 0ull;
                u64 nzd = __ballot(D != 0ull);
                while (nzd) {
                    int j = __builtin_ctzll(nzd);
                    nzd &= nzd - 1;
                    if ((alive >> j) & 1ull) alive &= ~rdlane64(D, j);
                }
            }
        }
        if (lane == 0) sKeep[c] = alive;
        // scatter: entries sourced in this chunk from alive rows -> future chunks' sR
        u32 cnt = cnt0;                               // uniform
#pragma unroll
        for (int s = 0; s < ECR; ++s) {
            if ((u32)(s * 64 + lane) < cnt) {
                u32 pk = (u32)E0[s].x;
                if ((alive >> (pk & 63u)) & 1ull) atomicOr((u64*)&sR[pk >> 6], E0[s].y);
            }
        }
        if (cnt > (u32)(64 * ECR)) {                  // rare tail beyond register slots
            for (u32 e = (u32)(64 * ECR) + (u32)lane; e < cnt; e += 64u) {
                ulonglong2 E = epack[c * CAP + e];
                u32 pk = (u32)E.x;
                if ((alive >> (pk & 63u)) & 1ull) atomicOr((u64*)&sR[pk >> 6], E.y);
            }
        }
        // rotate pipeline
#pragma unroll
        for (int s = 0; s < ECR; ++s) { E0[s] = E1[s]; E1[s] = E2[s]; }
        DP0 = DP1; DP1 = DP2; cnt0 = cnt1; cnt1 = cnt2;
    }
    __syncthreads();
    for (int i = lane; i < NCH; i += 64) keepw[i] = sKeep[i];
}

// ---------------- K7: emit top-1000 (kept in order, then -inf padding) ----------------
__global__ __launch_bounds__(1024) void k_out(const u64* __restrict__ keepw,
                                              const float4* __restrict__ sB,
                                              const float* __restrict__ sS,
                                              float* __restrict__ out) {
    __shared__ u32 wpre[NCH + 1];
    int t = threadIdx.x;
    if (t == 0) {
        u32 run = 0;
        for (int w = 0; w < NCH; ++w) { wpre[w] = run; run += (u32)__popcll(keepw[w]); }
        wpre[NCH] = run;
    }
    __syncthreads();
    u32 nk = wpre[NCH];
    for (int i = t; i < K_TOT; i += 1024) {
        int w = i >> 6, b = i & 63;
        u64 kw = keepw[w];
        u32 kb = wpre[w] + (u32)__popcll(kw & ((1ull << b) - 1ull));
        bool kp = (kw >> b) & 1ull;
        if (kp) {
            if (kb < 1000u) {
                float4 bx = sB[i];
                out[kb * 4 + 0] = bx.x; out[kb * 4 + 1] = bx.y;
                out[kb * 4 + 2] = bx.z; out[kb * 4 + 3] = bx.w;
                out[4000 + kb] = sS[i];
            }
        } else {
            u32 q = (u32)i - kb;
            u32 slot = nk + q;
            if (slot < 1000u) {
                float4 bx = sB[i];
                out[slot * 4 + 0] = bx.x; out[slot * 4 + 1] = bx.y;
                out[slot * 4 + 2] = bx.z; out[slot * 4 + 3] = bx.w;
                out[4000 + slot] = -INFINITY;
            }
        }
    }
}

// ---------------- workspace layout ----------------
static constexpr size_t al256(size_t x) { return (x + 255) & ~(size_t)255; }
static constexpr size_t KB4 = (size_t)K_TOT * 4;
static constexpr size_t KB16 = (size_t)K_TOT * 16;
// zeroed region:
static constexpr size_t O_RANK = 0;
static constexpr size_t O_PRAW = al256(O_RANK + KB4);
static constexpr size_t O_ECNT = al256(O_PRAW + KB4);
static constexpr size_t O_DCNT = al256(O_ECNT + (size_t)NCH * 4);
static constexpr size_t O_DMASK = al256(O_DCNT + (size_t)NCH * 4);
static constexpr size_t O_HIST = al256(O_DMASK + (size_t)NCH * 8);
static constexpr size_t O_CGT = al256(O_HIST + (size_t)3 * 2048 * 4);
static constexpr size_t O_GCNT = al256(O_CGT + 3 * 4);
static constexpr size_t MEMSET_BYTES = al256(O_GCNT + 3 * 4);
// non-zeroed region:
static constexpr size_t O_TINFO = MEMSET_BYTES;
static constexpr size_t O_SEL = al256(O_TINFO + 6 * 4);
static constexpr size_t O_GIDX = al256(O_SEL + KB4);
static constexpr size_t O_GKEY = al256(O_GIDX + (size_t)3 * GCAP * 4);
static constexpr size_t O_CANDB = al256(O_GKEY + (size_t)3 * GCAP * 4);
static constexpr size_t O_CANDS = al256(O_CANDB + KB16);
static constexpr size_t O_CANDV = al256(O_CANDS + KB4);
static constexpr size_t O_CANDA = al256(O_CANDV + KB4);
static constexpr size_t O_SB = al256(O_CANDA + KB4);
static constexpr size_t O_SAREA = al256(O_SB + KB16);
static constexpr size_t O_SS = al256(O_SAREA + KB4);
static constexpr size_t O_SV = al256(O_SS + KB4);
static constexpr size_t O_VW = al256(O_SV + KB4);
static constexpr size_t O_KW = al256(O_VW + (size_t)NCH * 8);
static constexpr size_t O_DIAG = al256(O_KW + (size_t)NCH * 8);
static constexpr size_t O_EPACK = al256(O_DIAG + (size_t)(NCH * 64) * 8);
static constexpr size_t O_DPACK = al256(O_EPACK + (size_t)NCH * CAP * 16);

extern "C" void kernel_launch(void* const* d_in, const int* in_sizes, int n_in,
                              void* d_out, int out_size, void* d_ws, size_t ws_size,
                              hipStream_t stream) {
    const float* scores = (const float*)d_in[0];
    const float4* deltas = (const float4*)d_in[1];
    const float4* anchors = (const float4*)d_in[2];
    float* out = (float*)d_out;
    char* ws = (char*)d_ws;

    u32* rank = (u32*)(ws + O_RANK);
    u32* Praw = (u32*)(ws + O_PRAW);
    u32* ecnt = (u32*)(ws + O_ECNT);
    u32* dcnt = (u32*)(ws + O_DCNT);
    u64* dmask = (u64*)(ws + O_DMASK);
    u32* hist3 = (u32*)(ws + O_HIST);
    u32* cgt = (u32*)(ws + O_CGT);
    u32* gcnt = (u32*)(ws + O_GCNT);
    u32* tinfo = (u32*)(ws + O_TINFO);
    u32* sel = (u32*)(ws + O_SEL);
    u32* gidx = (u32*)(ws + O_GIDX);
    u32* gkey = (u32*)(ws + O_GKEY);
    float4* candB = (float4*)(ws + O_CANDB);
    float* candS = (float*)(ws + O_CANDS);
    u32* candV = (u32*)(ws + O_CANDV);
    u32* candA = (u32*)(ws + O_CANDA);
    float4* sB = (float4*)(ws + O_SB);
    float* sArea = (float*)(ws + O_SAREA);
    float* sS = (float*)(ws + O_SS);
    u32* sV = (u32*)(ws + O_SV);
    u64* vwords = (u64*)(ws + O_VW);
    u64* keepw = (u64*)(ws + O_KW);
    u64* diag = (u64*)(ws + O_DIAG);
    ulonglong2* epack = (ulonglong2*)(ws + O_EPACK);
    ulonglong2* dpack = (ulonglong2*)(ws + O_DPACK);

    hipMemsetAsync(ws, 0, MEMSET_BYTES, stream);

    const int NBLK = (K_TOT + 255) / 256;  // 33
    k_hist<<<156, 1024, 0, stream>>>(scores, hist3);
    k_thresh<<<3, 1024, 0, stream>>>(hist3, tinfo);
    k_gather<<<159, 1024, 0, stream>>>(scores, tinfo, sel, cgt, gcnt, gidx, gkey);
    k_final<<<3, 1024, 0, stream>>>(gidx, gkey, gcnt, tinfo, sel);
    k_decode<<<NBLK, 256, 0, stream>>>(scores, deltas, anchors, sel, candB, candS, candV, candA);
    k_rank_lvl<<<dim3(8, 8, 5), 256, 0, stream>>>(candS, candA, Praw);
    k_rank_glob<<<dim3(NBLK, NBLK), 256, 0, stream>>>(candS, candV, Praw, rank);
    k_scatter<<<NBLK, 256, 0, stream>>>(candB, candS, candV, rank, sB, sArea, sS, sV);
    k_vwords<<<NCH, 64, 0, stream>>>(sV, vwords);
    k_mask<<<dim3(NCH, NBLK), 256, 0, stream>>>(sB, sArea, diag, ecnt, epack, dcnt, dmask, dpack);
    k_scan<<<1, 64, 0, stream>>>(diag, vwords, ecnt, epack, dcnt, dmask, dpack, keepw);
    k_out<<<1, 1024, 0, stream>>>(keepw, sB, sS, out);
}

// Round 10
// 225.982 us; speedup vs baseline: 1.2063x; 1.2063x over previous
//
#include <hip/hip_runtime.h>
#include <math.h>

typedef unsigned int u32;
typedef unsigned long long u64;
typedef unsigned char u8;

#define K_TOT 8382
#define NCH 131      // 131 chunks of 64 rows
#define CAP 1024     // per-source-chunk off-diag entry capacity (global)
#define EC 64        // per-source-chunk entries staged to LDS (1 per lane)
#define DC 8         // per-chunk intra-chunk (diag) suppressor list capacity
#define GCAP 32768   // per-level threshold-bin candidate capacity
#define IMGSZ 800.0f

__device__ __constant__ int LOFF[5] = {0, 120000, 150000, 157500, 159375};
__device__ __constant__ int LCNT[5] = {120000, 30000, 7500, 1875, 507};
__device__ __constant__ int KSEL[5] = {2000, 2000, 2000, 1875, 507};
__device__ __constant__ int SELB[5] = {0, 2000, 4000, 6000, 7875};
__device__ __constant__ int HBS[4] = {0, 118, 148, 156};    // k_hist block starts (levels 0..2)
__device__ __constant__ int GBS[6] = {0, 118, 148, 156, 158, 159};  // k_gather block starts

static __device__ __forceinline__ u32 fkey(float x) {
    u32 u = __float_as_uint(x);
    u32 m = (u32)(((int)u) >> 31) | 0x80000000u;
    return u ^ m;
}

static __device__ __forceinline__ int lvl_of(int s) {
    return (s < 2000) ? 0 : (s < 4000) ? 1 : (s < 6000) ? 2 : (s < 7875) ? 3 : 4;
}

// scalar-path 64-bit readlane (uniform lane index -> v_readlane)
static __device__ __forceinline__ u64 rdlane64(u64 v, int j) {
    u32 lo = (u32)__builtin_amdgcn_readlane((int)(u32)v, j);
    u32 hi = (u32)__builtin_amdgcn_readlane((int)(u32)(v >> 32), j);
    return ((u64)hi << 32) | (u64)lo;
}

// Parallel reverse-inclusive scan over hist[0..m-1] (from top bin down);
// finds bin with suffix-cum >= need. Out: sv[0]=bin, sv[1]=remaining ties to take.
static __device__ __forceinline__ void thresh_scan(const u32* hist, u32* scanbuf, int m,
                                                   u32 need, u32* sv, int t) {
    for (int i = t; i < m; i += 1024) scanbuf[i] = hist[m - 1 - i];
    __syncthreads();
    for (int ofs = 1; ofs < m; ofs <<= 1) {
        int i0 = t, i1 = t + 1024;
        u32 a0 = 0, a1 = 0;
        if (i0 < m && i0 >= ofs) a0 = scanbuf[i0 - ofs];
        if (i1 < m && i1 >= ofs) a1 = scanbuf[i1 - ofs];
        __syncthreads();
        if (i0 < m && i0 >= ofs) scanbuf[i0] += a0;
        if (i1 < m && i1 >= ofs) scanbuf[i1] += a1;
        __syncthreads();
    }
    for (int i = t; i < m; i += 1024) {
        u32 inc = scanbuf[i];
        u32 exc = i ? scanbuf[i - 1] : 0;
        if (inc >= need && exc < need) { sv[0] = (u32)(m - 1 - i); sv[1] = need - exc; }
    }
    __syncthreads();
}

// ---------------- K1a: parallel coarse histogram (top 11 key bits), levels 0..2 ----------------
__global__ __launch_bounds__(1024) void k_hist(const float* __restrict__ scores,
                                               u32* __restrict__ hist3) {
    __shared__ u32 lh[2048];
    int t = threadIdx.x;
    lh[t] = 0; lh[t + 1024] = 0;
    __syncthreads();
    int b = blockIdx.x;
    int l = (b < HBS[1]) ? 0 : (b < HBS[2]) ? 1 : 2;
    int i = (b - HBS[l]) * 1024 + t;
    if (i < LCNT[l]) atomicAdd(&lh[fkey(scores[LOFF[l] + i]) >> 21], 1u);
    __syncthreads();
    u32* h = hist3 + l * 2048;
    if (lh[t]) atomicAdd(&h[t], lh[t]);
    if (lh[t + 1024]) atomicAdd(&h[t + 1024], lh[t + 1024]);
}

// ---------------- K1b: coarse threshold per level ----------------
__global__ __launch_bounds__(1024) void k_thresh(const u32* __restrict__ hist3,
                                                 u32* __restrict__ tinfo) {
    __shared__ u32 scanbuf[2048];
    __shared__ u32 sv[2];
    int l = blockIdx.x;
    int t = threadIdx.x;
    thresh_scan(hist3 + l * 2048, scanbuf, 2048, (u32)KSEL[l], sv, t);
    if (t == 0) { tinfo[l * 2] = sv[0]; tinfo[l * 2 + 1] = sv[1]; }
}

// ---------------- K1c: classify; strict-greater -> sel, threshold-bin -> candidate buf ----------------
__global__ __launch_bounds__(1024) void k_gather(const float* __restrict__ scores,
                                                 const u32* __restrict__ tinfo,
                                                 u32* __restrict__ sel, u32* __restrict__ cgt,
                                                 u32* __restrict__ gcnt, u32* __restrict__ gidx,
                                                 u32* __restrict__ gkey) {
    int b = blockIdx.x;
    int l = (b < GBS[1]) ? 0 : (b < GBS[2]) ? 1 : (b < GBS[3]) ? 2 : (b < GBS[4]) ? 3 : 4;
    int i = (b - GBS[l]) * 1024 + threadIdx.x;
    if (i >= LCNT[l]) return;
    int off = LOFF[l], sb = SELB[l];
    if (l >= 3) { sel[sb + i] = (u32)(off + i); return; }  // take-all levels
    u32 ky = fkey(scores[off + i]);
    u32 b1 = tinfo[l * 2];
    u32 top = ky >> 21;
    if (top > b1) {
        u32 p = atomicAdd(&cgt[l], 1u);
        sel[sb + p] = (u32)(off + i);          // set membership only; order fixed by P later
    } else if (top == b1) {
        u32 e = atomicAdd(&gcnt[l], 1u);
        if (e < GCAP) { gidx[l * GCAP + e] = (u32)i; gkey[l * GCAP + e] = ky; }
    }
}

// ---------------- K1d: exact refine within threshold bin (mid 11 + low 10 bits) ----------------
__global__ __launch_bounds__(1024) void k_final(const u32* __restrict__ gidx,
                                                const u32* __restrict__ gkey,
                                                const u32* __restrict__ gcnt,
                                                const u32* __restrict__ tinfo,
                                                u32* __restrict__ sel) {
    __shared__ u32 hist[2048];
    __shared__ u32 scanbuf[2048];
    __shared__ u32 eqbuf[1024];
    __shared__ u32 sv[2];
    __shared__ u32 c2, ceq;
    int l = blockIdx.x;
    int t = threadIdx.x;
    int k = KSEL[l], sb = SELB[l], off = LOFF[l];
    u32 m = gcnt[l]; if (m > GCAP) m = GCAP;
    u32 b1 = tinfo[l * 2];
    u32 need = tinfo[l * 2 + 1];
    const u32* kb = gkey + l * GCAP;
    const u32* ib = gidx + l * GCAP;
    // mid 11 bits
    hist[t] = 0; hist[t + 1024] = 0; __syncthreads();
    for (u32 e = t; e < m; e += 1024) atomicAdd(&hist[(kb[e] >> 10) & 2047u], 1u);
    __syncthreads();
    thresh_scan(hist, scanbuf, 2048, need, sv, t);
    u32 b2 = sv[0], need2 = sv[1];
    __syncthreads();
    // low 10 bits
    hist[t] = 0; __syncthreads();
    for (u32 e = t; e < m; e += 1024) {
        u32 ky = kb[e];
        if (((ky >> 10) & 2047u) == b2) atomicAdd(&hist[ky & 1023u], 1u);
    }
    __syncthreads();
    thresh_scan(hist, scanbuf, 1024, need2, sv, t);
    u32 T = (b1 << 21) | (b2 << 10) | sv[0];
    u32 take = sv[1];
    if (t == 0) { c2 = 0; ceq = 0; }
    __syncthreads();
    u32 nGTbin = need - take;
    u32 base2 = (u32)sb + (u32)k - need;   // after strict-greater-bin entries
    for (u32 e = t; e < m; e += 1024) {
        u32 ky = kb[e];
        if (ky > T) { u32 p = atomicAdd(&c2, 1u); sel[base2 + p] = (u32)off + ib[e]; }
        else if (ky == T) { u32 q = atomicAdd(&ceq, 1u); if (q < 1024) eqbuf[q] = ib[e]; }
    }
    __syncthreads();
    if (t == 0) {
        int n = (ceq > 1024u) ? 1024 : (int)ceq;
        for (int a = 1; a < n; ++a) {  // ascending insertion sort; tie count tiny
            u32 v = eqbuf[a]; int bq = a - 1;
            while (bq >= 0 && eqbuf[bq] > v) { eqbuf[bq + 1] = eqbuf[bq]; --bq; }
            eqbuf[bq + 1] = v;
        }
        for (u32 q = 0; q < take; ++q) sel[base2 + nGTbin + q] = (u32)off + eqbuf[q];
    }
}

// ---------------- K2: decode selected boxes (exact reference op order) ----------------
__global__ void k_decode(const float* __restrict__ scores, const float4* __restrict__ deltas,
                         const float4* __restrict__ anchors, const u32* __restrict__ sel,
                         float4* __restrict__ candB, float* __restrict__ candS,
                         u32* __restrict__ candV, u32* __restrict__ candA) {
    int s = blockIdx.x * 256 + threadIdx.x;
    if (s >= K_TOT) return;
    u32 a = sel[s];
    float4 an = anchors[a];
    float4 dl = deltas[a];
    float sc = scores[a];
    float w = __fsub_rn(an.z, an.x), h = __fsub_rn(an.w, an.y);
    float cx = __fadd_rn(an.x, __fmul_rn(0.5f, w));
    float cy = __fadd_rn(an.y, __fmul_rn(0.5f, h));
    const float CLIPV = (float)4.1351665567423563;  // log(1000/16) as f32
    float dw = fminf(dl.z, CLIPV);
    float dh = fminf(dl.w, CLIPV);
    float px = __fadd_rn(cx, __fmul_rn(dl.x, w));
    float py = __fadd_rn(cy, __fmul_rn(dl.y, h));
    float pw = __fmul_rn((float)exp((double)dw), w);
    float ph = __fmul_rn((float)exp((double)dh), h);
    float x1 = __fsub_rn(px, __fmul_rn(0.5f, pw));
    float y1 = __fsub_rn(py, __fmul_rn(0.5f, ph));
    float x2 = __fadd_rn(px, __fmul_rn(0.5f, pw));
    float y2 = __fadd_rn(py, __fmul_rn(0.5f, ph));
    x1 = fminf(fmaxf(x1, 0.0f), IMGSZ);
    y1 = fminf(fmaxf(y1, 0.0f), IMGSZ);
    x2 = fminf(fmaxf(x2, 0.0f), IMGSZ);
    y2 = fminf(fmaxf(y2, 0.0f), IMGSZ);
    bool valid = (__fsub_rn(x2, x1) >= 0.001f) && (__fsub_rn(y2, y1) >= 0.001f);
    candB[s] = make_float4(x1, y1, x2, y2);
    candS[s] = sc;
    candV[s] = valid ? 1u : 0u;
    candA[s] = a;
}

// ---------------- K3a: within-level rank (tiled pairwise count) ----------------
__global__ __launch_bounds__(256) void k_rank_lvl(const float* __restrict__ candS,
                                                  const u32* __restrict__ candA,
                                                  u32* __restrict__ Praw) {
    __shared__ u64 tile[256];
    int l = blockIdx.z;
    int cnt = KSEL[l], base = SELB[l];
    int tx = blockIdx.x * 256;
    int ty = blockIdx.y * 256;
    if (tx >= cnt || ty >= cnt) return;
    int t = threadIdx.x;
    u64 Aj = ~0ull;  // sentinel: never < any real key
    if (tx + t < cnt) {
        int j = base + tx + t;
        Aj = ((u64)(~fkey(candS[j])) << 32) | (u64)candA[j];
    }
    tile[t] = Aj;
    __syncthreads();
    int si = ty + t;
    if (si >= cnt) return;
    int s = base + si;
    u64 A = ((u64)(~fkey(candS[s])) << 32) | (u64)candA[s];
    int r = 0;
#pragma unroll 8
    for (int q = 0; q < 256; ++q) r += (tile[q] < A);
    if (r) atomicAdd(&Praw[s], (u32)r);
}

// ---------------- K3b: global rank by (masked score desc, position asc) ----------------
__global__ __launch_bounds__(256) void k_rank_glob(const float* __restrict__ candS,
                                                   const u32* __restrict__ candV,
                                                   const u32* __restrict__ Praw,
                                                   u32* __restrict__ rank) {
    __shared__ u64 colB[256];
    int t = threadIdx.x;
    int cj = blockIdx.x * 256 + t;
    u64 B = ~0ull;
    if (cj < K_TOT) {
        u32 smk = candV[cj] ? fkey(candS[cj]) : 0x007FFFFFu;  // fkey(-inf)
        u32 Pj = (u32)SELB[lvl_of(cj)] + Praw[cj];
        B = ((u64)(~smk) << 32) | (u64)Pj;
    }
    colB[t] = B;
    __syncthreads();
    int s = blockIdx.y * 256 + t;
    if (s >= K_TOT) return;
    u32 smk = candV[s] ? fkey(candS[s]) : 0x007FFFFFu;
    u32 Ps = (u32)SELB[lvl_of(s)] + Praw[s];
    u64 myB = ((u64)(~smk) << 32) | (u64)Ps;
    int cnt = 0;
#pragma unroll 8
    for (int j = 0; j < 256; ++j) cnt += (colB[j] < myB);
    if (cnt) atomicAdd(&rank[s], (u32)cnt);
}

// ---------------- K4: scatter into sorted order ----------------
// Reference's fmask slice is all zeros -> NMS on raw clipped boxes (no level offsets).
__global__ void k_scatter(const float4* __restrict__ candB, const float* __restrict__ candS,
                          const u32* __restrict__ candV, const u32* __restrict__ rank,
                          float4* __restrict__ sB, float* __restrict__ sArea,
                          float* __restrict__ sS, u32* __restrict__ sV) {
    int s = blockIdx.x * 256 + threadIdx.x;
    if (s >= K_TOT) return;
    u32 r = rank[s];
    float4 b = candB[s];
    float area = __fmul_rn(__fsub_rn(b.z, b.x), __fsub_rn(b.w, b.y));
    sB[r] = b; sArea[r] = area; sS[r] = candS[s]; sV[r] = candV[s];
}

// ---------------- K4b: valid bits -> words ----------------
__global__ void k_vwords(const u32* __restrict__ sV, u64* __restrict__ vwords) {
    int i = blockIdx.x * 64 + threadIdx.x;
    bool pred = (i < K_TOT) && sV[i];
    u64 bw = __ballot(pred);
    if (threadIdx.x == 0) vwords[blockIdx.x] = bw;
}

// ---------------- K5: suppression bits -> packed entry lists ----------------
// off-diag: bucketed by SOURCE chunk, 16B entries {row|target<<6, bits}.
// diag (intra-chunk): 16B list entries {lane, bits} + dmask; full diag[] kept as fallback.
__global__ __launch_bounds__(256) void k_mask(const float4* __restrict__ sB,
                                              const float* __restrict__ sArea,
                                              u64* __restrict__ diag, u32* __restrict__ ecnt,
                                              ulonglong2* __restrict__ epack,
                                              u32* __restrict__ dcnt, u64* __restrict__ dmask,
                                              ulonglong2* __restrict__ dpack) {
    __shared__ float4 cb[64];
    __shared__ float ca[64];
    int wd = blockIdx.x;   // target word (column chunk)
    int t = threadIdx.x;
    if (t < 64) {
        int j = wd * 64 + t;
        if (j < K_TOT) { cb[t] = sB[j]; ca[t] = sArea[j]; }
        else { cb[t] = make_float4(0.f, 0.f, 0.f, 0.f); ca[t] = 0.f; }
    }
    __syncthreads();
    int i = blockIdx.y * 256 + t;
    if (i >= K_TOT) return;
    int dwr = i >> 6;
    if (wd < dwr) return;  // strictly upper-triangular
    float4 bi = sB[i];
    float ai = sArea[i];
    u64 bits = 0;
    int jbase = wd * 64;
    for (int j2 = 0; j2 < 64; ++j2) {
        int j = jbase + j2;
        if (j > i && j < K_TOT) {
            float4 bj = cb[j2];
            float ltx = fmaxf(bi.x, bj.x), lty = fmaxf(bi.y, bj.y);
            float rbx = fminf(bi.z, bj.z), rby = fminf(bi.w, bj.w);
            float wx = fmaxf(__fsub_rn(rbx, ltx), 0.0f);
            float wy = fmaxf(__fsub_rn(rby, lty), 0.0f);
            float inter = __fmul_rn(wx, wy);
            if (inter > 0.0f) {
                float uni = __fsub_rn(__fadd_rn(ai, ca[j2]), inter);
                float iou = inter / uni;  // IEEE f32 div, matches reference
                if (iou > 0.7f) bits |= (1ull << j2);
            }
        }
    }
    if (wd == dwr) {
        diag[i] = bits;  // always stored (overflow fallback)
        if (bits != 0ull) {
            u32 p = atomicAdd(&dcnt[dwr], 1u);
            if (p < DC) dpack[dwr * DC + p] = make_ulonglong2((u64)(i & 63), bits);
            atomicOr(&dmask[dwr], 1ull << (i & 63));
        }
    } else if (bits != 0ull) {
        u32 p = atomicAdd(&ecnt[dwr], 1u);
        if (p < CAP) epack[dwr * CAP + p] = make_ulonglong2((u64)((i & 63) | (wd << 6)), bits);
    }
}

// ---------------- K6: sequential NMS scan — MLP-batched staging, all-LDS serial loop ----------------
__global__ __launch_bounds__(64) void k_scan(const u64* __restrict__ diag,
                                             const u64* __restrict__ vwords,
                                             const u32* __restrict__ ecnt,
                                             const ulonglong2* __restrict__ epack,
                                             const u32* __restrict__ dcnt,
                                             const u64* __restrict__ dmask,
                                             const ulonglong2* __restrict__ dpack,
                                             u64* __restrict__ keepw) {
    __shared__ u64 sVw[NCH];
    __shared__ u32 sCnt[NCH];
    __shared__ u32 sDn[NCH];
    __shared__ u64 sDm[NCH];
    __shared__ ulonglong2 sEpack[NCH * EC];   // 134 KB
    __shared__ ulonglong2 sDpack[NCH * DC];   // 16.8 KB
    volatile __shared__ u64 sR[NCH];          // accumulated incoming suppression per chunk
    __shared__ u64 sKeep[NCH];
    int lane = threadIdx.x;
    // small arrays: 3 straight-line batched rounds (loads issued together)
    {
        int i0 = lane, i1 = lane + 64, i2 = lane + 128;
        bool p2 = (i2 < NCH);
        u64 v0 = vwords[i0], v1 = vwords[i1], v2 = p2 ? vwords[i2] : 0;
        u32 c0 = ecnt[i0], c1 = ecnt[i1], c2 = p2 ? ecnt[i2] : 0;
        u32 d0 = dcnt[i0], d1 = dcnt[i1], d2 = p2 ? dcnt[i2] : 0;
        u64 m0 = dmask[i0], m1 = dmask[i1], m2 = p2 ? dmask[i2] : 0;
        sVw[i0] = v0; sCnt[i0] = (c0 > CAP) ? CAP : c0; sDn[i0] = d0; sDm[i0] = m0; sR[i0] = 0;
        sVw[i1] = v1; sCnt[i1] = (c1 > CAP) ? CAP : c1; sDn[i1] = d1; sDm[i1] = m1; sR[i1] = 0;
        if (p2) { sVw[i2] = v2; sCnt[i2] = (c2 > CAP) ? CAP : c2; sDn[i2] = d2; sDm[i2] = m2; sR[i2] = 0; }
    }
    // epack staging: 131 chunk-rounds, 16 independent loads in flight per batch
    for (int base = 0; base < NCH; base += 16) {
        ulonglong2 tmp[16];
        int nb = NCH - base; if (nb > 16) nb = 16;
#pragma unroll
        for (int b = 0; b < 16; ++b)
            if (b < nb) tmp[b] = epack[(size_t)(base + b) * CAP + lane];
#pragma unroll
        for (int b = 0; b < 16; ++b)
            if (b < nb) sEpack[(base + b) * EC + lane] = tmp[b];
    }
    // dpack staging: NCH*DC = 1048 entries (global layout contiguous), batch 8
    for (int base = 0; base < NCH * DC; base += 64 * 8) {
        ulonglong2 tmp[8];
#pragma unroll
        for (int b = 0; b < 8; ++b) {
            int i = base + b * 64 + lane;
            if (i < NCH * DC) tmp[b] = dpack[i];
        }
#pragma unroll
        for (int b = 0; b < 8; ++b) {
            int i = base + b * 64 + lane;
            if (i < NCH * DC) sDpack[i] = tmp[b];
        }
    }
    __syncthreads();
    // serial scan: zero global accesses (except rare overflow fallbacks)
    for (int c = 0; c < NCH; ++c) {
        u32 cnt = sCnt[c];                     // uniform
        u32 dn = sDn[c];                       // uniform
        ulonglong2 E = sEpack[c * EC + lane];  // junk beyond cnt: gated below
        ulonglong2 DP = (lane < DC) ? sDpack[c * DC + lane] : make_ulonglong2(~0ull, 0ull);
        u64 vw = sVw[c];
        u64 alive = vw & ~sR[c];               // the ONLY state-dependent read
        if (dn) {
            if (dn <= (u32)DC) {
                u64 dm = sDm[c];               // uniform: rows with nonzero intra-chunk bits
                u32 ml = ((u32)lane < dn) ? (u32)DP.x : 0xFFu;
                while (dm) {
                    int j = __builtin_ctzll(dm);
                    dm &= dm - 1;
                    if ((alive >> j) & 1ull) { // uniform branch
                        u64 selm = __ballot(ml == (u32)j);
                        int src = __builtin_ctzll(selm);
                        alive &= ~rdlane64(DP.y, src);
                    }
                }
            } else {                            // overflow: read full diag words (rare)
                int r = c * 64 + lane;
                u64 D = (r < K_TOT) ? diag[r] : 0ull;
                u64 nzd = __ballot(D != 0ull);
                while (nzd) {
                    int j = __builtin_ctzll(nzd);
                    nzd &= nzd - 1;
                    if ((alive >> j) & 1ull) alive &= ~rdlane64(D, j);
                }
            }
        }
        if (lane == 0) sKeep[c] = alive;
        // scatter: entries sourced in this chunk from alive rows -> future chunks' sR
        if ((u32)lane < cnt && ((alive >> ((u32)E.x & 63u)) & 1ull))
            atomicOr((u64*)&sR[(u32)E.x >> 6], E.y);
        if (cnt > (u32)EC) {                    // rare tail beyond LDS-staged entries
            for (u32 e = (u32)EC + (u32)lane; e < cnt; e += 64u) {
                ulonglong2 Et = epack[(size_t)c * CAP + e];
                u32 pk = (u32)Et.x;
                if ((alive >> (pk & 63u)) & 1ull) atomicOr((u64*)&sR[pk >> 6], Et.y);
            }
        }
    }
    __syncthreads();
    for (int i = lane; i < NCH; i += 64) keepw[i] = sKeep[i];
}

// ---------------- K7: emit top-1000 (kept in order, then -inf padding) ----------------
__global__ __launch_bounds__(1024) void k_out(const u64* __restrict__ keepw,
                                              const float4* __restrict__ sB,
                                              const float* __restrict__ sS,
                                              float* __restrict__ out) {
    __shared__ u32 wpre[NCH + 1];
    int t = threadIdx.x;
    if (t == 0) {
        u32 run = 0;
        for (int w = 0; w < NCH; ++w) { wpre[w] = run; run += (u32)__popcll(keepw[w]); }
        wpre[NCH] = run;
    }
    __syncthreads();
    u32 nk = wpre[NCH];
    for (int i = t; i < K_TOT; i += 1024) {
        int w = i >> 6, b = i & 63;
        u64 kw = keepw[w];
        u32 kb = wpre[w] + (u32)__popcll(kw & ((1ull << b) - 1ull));
        bool kp = (kw >> b) & 1ull;
        if (kp) {
            if (kb < 1000u) {
                float4 bx = sB[i];
                out[kb * 4 + 0] = bx.x; out[kb * 4 + 1] = bx.y;
                out[kb * 4 + 2] = bx.z; out[kb * 4 + 3] = bx.w;
                out[4000 + kb] = sS[i];
            }
        } else {
            u32 q = (u32)i - kb;
            u32 slot = nk + q;
            if (slot < 1000u) {
                float4 bx = sB[i];
                out[slot * 4 + 0] = bx.x; out[slot * 4 + 1] = bx.y;
                out[slot * 4 + 2] = bx.z; out[slot * 4 + 3] = bx.w;
                out[4000 + slot] = -INFINITY;
            }
        }
    }
}

// ---------------- workspace layout ----------------
static constexpr size_t al256(size_t x) { return (x + 255) & ~(size_t)255; }
static constexpr size_t KB4 = (size_t)K_TOT * 4;
static constexpr size_t KB16 = (size_t)K_TOT * 16;
// zeroed region:
static constexpr size_t O_RANK = 0;
static constexpr size_t O_PRAW = al256(O_RANK + KB4);
static constexpr size_t O_ECNT = al256(O_PRAW + KB4);
static constexpr size_t O_DCNT = al256(O_ECNT + (size_t)NCH * 4);
static constexpr size_t O_DMASK = al256(O_DCNT + (size_t)NCH * 4);
static constexpr size_t O_HIST = al256(O_DMASK + (size_t)NCH * 8);
static constexpr size_t O_CGT = al256(O_HIST + (size_t)3 * 2048 * 4);
static constexpr size_t O_GCNT = al256(O_CGT + 3 * 4);
static constexpr size_t MEMSET_BYTES = al256(O_GCNT + 3 * 4);
// non-zeroed region:
static constexpr size_t O_TINFO = MEMSET_BYTES;
static constexpr size_t O_SEL = al256(O_TINFO + 6 * 4);
static constexpr size_t O_GIDX = al256(O_SEL + KB4);
static constexpr size_t O_GKEY = al256(O_GIDX + (size_t)3 * GCAP * 4);
static constexpr size_t O_CANDB = al256(O_GKEY + (size_t)3 * GCAP * 4);
static constexpr size_t O_CANDS = al256(O_CANDB + KB16);
static constexpr size_t O_CANDV = al256(O_CANDS + KB4);
static constexpr size_t O_CANDA = al256(O_CANDV + KB4);
static constexpr size_t O_SB = al256(O_CANDA + KB4);
static constexpr size_t O_SAREA = al256(O_SB + KB16);
static constexpr size_t O_SS = al256(O_SAREA + KB4);
static constexpr size_t O_SV = al256(O_SS + KB4);
static constexpr size_t O_VW = al256(O_SV + KB4);
static constexpr size_t O_KW = al256(O_VW + (size_t)NCH * 8);
static constexpr size_t O_DIAG = al256(O_KW + (size_t)NCH * 8);
static constexpr size_t O_EPACK = al256(O_DIAG + (size_t)(NCH * 64) * 8);
static constexpr size_t O_DPACK = al256(O_EPACK + (size_t)NCH * CAP * 16);

extern "C" void kernel_launch(void* const* d_in, const int* in_sizes, int n_in,
                              void* d_out, int out_size, void* d_ws, size_t ws_size,
                              hipStream_t stream) {
    const float* scores = (const float*)d_in[0];
    const float4* deltas = (const float4*)d_in[1];
    const float4* anchors = (const float4*)d_in[2];
    float* out = (float*)d_out;
    char* ws = (char*)d_ws;

    u32* rank = (u32*)(ws + O_RANK);
    u32* Praw = (u32*)(ws + O_PRAW);
    u32* ecnt = (u32*)(ws + O_ECNT);
    u32* dcnt = (u32*)(ws + O_DCNT);
    u64* dmask = (u64*)(ws + O_DMASK);
    u32* hist3 = (u32*)(ws + O_HIST);
    u32* cgt = (u32*)(ws + O_CGT);
    u32* gcnt = (u32*)(ws + O_GCNT);
    u32* tinfo = (u32*)(ws + O_TINFO);
    u32* sel = (u32*)(ws + O_SEL);
    u32* gidx = (u32*)(ws + O_GIDX);
    u32* gkey = (u32*)(ws + O_GKEY);
    float4* candB = (float4*)(ws + O_CANDB);
    float* candS = (float*)(ws + O_CANDS);
    u32* candV = (u32*)(ws + O_CANDV);
    u32* candA = (u32*)(ws + O_CANDA);
    float4* sB = (float4*)(ws + O_SB);
    float* sArea = (float*)(ws + O_SAREA);
    float* sS = (float*)(ws + O_SS);
    u32* sV = (u32*)(ws + O_SV);
    u64* vwords = (u64*)(ws + O_VW);
    u64* keepw = (u64*)(ws + O_KW);
    u64* diag = (u64*)(ws + O_DIAG);
    ulonglong2* epack = (ulonglong2*)(ws + O_EPACK);
    ulonglong2* dpack = (ulonglong2*)(ws + O_DPACK);

    hipMemsetAsync(ws, 0, MEMSET_BYTES, stream);

    const int NBLK = (K_TOT + 255) / 256;  // 33
    k_hist<<<156, 1024, 0, stream>>>(scores, hist3);
    k_thresh<<<3, 1024, 0, stream>>>(hist3, tinfo);
    k_gather<<<159, 1024, 0, stream>>>(scores, tinfo, sel, cgt, gcnt, gidx, gkey);
    k_final<<<3, 1024, 0, stream>>>(gidx, gkey, gcnt, tinfo, sel);
    k_decode<<<NBLK, 256, 0, stream>>>(scores, deltas, anchors, sel, candB, candS, candV, candA);
    k_rank_lvl<<<dim3(8, 8, 5), 256, 0, stream>>>(candS, candA, Praw);
    k_rank_glob<<<dim3(NBLK, NBLK), 256, 0, stream>>>(candS, candV, Praw, rank);
    k_scatter<<<NBLK, 256, 0, stream>>>(candB, candS, candV, rank, sB, sArea, sS, sV);
    k_vwords<<<NCH, 64, 0, stream>>>(sV, vwords);
    k_mask<<<dim3(NCH, NBLK), 256, 0, stream>>>(sB, sArea, diag, ecnt, epack, dcnt, dmask, dpack);
    k_scan<<<1, 64, 0, stream>>>(diag, vwords, ecnt, epack, dcnt, dmask, dpack, keepw);
    k_out<<<1, 1024, 0, stream>>>(keepw, sB, sS, out);
}